// Round 2
// baseline (492.335 us; speedup 1.0000x reference)
//
#include <hip/hip_runtime.h>
#include <hip/hip_bf16.h>
#include <cstdint>

// Problem constants
#define BATCH 32
#define CIN   256
#define COUT  256
#define HW    56
#define NEXP  8
#define HP    58           // padded spatial
#define KTOT  2304         // CIN*9

typedef __bf16 bf16x8 __attribute__((ext_vector_type(8)));
typedef float  f32x4  __attribute__((ext_vector_type(4)));
typedef unsigned short u16x8 __attribute__((ext_vector_type(8)));

static __device__ __forceinline__ unsigned short f32_to_bf16(float f) {
    uint32_t u = __builtin_bit_cast(uint32_t, f);
    return (unsigned short)((u + 0x7FFFu + ((u >> 16) & 1u)) >> 16);
}

// ---- x fp32 [b][i][56][56] -> xTp bf16 [b][58][58][i] (zero halo) + GAP row-sums ----
__global__ void transpose_kernel(const float* __restrict__ x, unsigned short* __restrict__ xtp,
                                 float* __restrict__ gap) {
    int hp = blockIdx.x;           // 0..57 padded row
    int ib = blockIdx.y;           // i-block of 32
    int b  = blockIdx.z;
    int t  = threadIdx.x;
    __shared__ float tile[32][57];
    bool in_h = (hp >= 1 && hp <= HW);
    if (in_h) {
        const float* src = x + (((size_t)b * CIN + ib * 32) * HW + (hp - 1)) * HW;
        for (int idx = t; idx < 32 * HW; idx += 256) {
            int il = idx / HW, w = idx - il * HW;
            tile[il][w] = src[(size_t)il * (HW * HW) + w];
        }
    }
    __syncthreads();
    unsigned short* dst = xtp + (((size_t)b * HP + hp) * HP) * CIN + ib * 32;
    for (int idx = t; idx < HP * 32; idx += 256) {
        int wp = idx >> 5, il = idx & 31;
        float v = 0.f;
        if (in_h && wp >= 1 && wp <= HW) v = tile[il][wp - 1];
        dst[(size_t)wp * CIN + il] = f32_to_bf16(v);
    }
    if (in_h) {
        // fused GAP partial: per-channel row sum -> atomic
        int c = t >> 3, j0 = t & 7;
        float s = 0.f;
        for (int j = j0; j < HW; j += 8) s += tile[c][j];
        s += __shfl_down(s, 4, 8);
        s += __shfl_down(s, 2, 8);
        s += __shfl_down(s, 1, 8);
        if (j0 == 0) atomicAdd(&gap[b * CIN + ib * 32 + c], s);
    }
}

// ---- routing[b][e] = sigmoid(gapsum[b]·fc_w[e]/3136 + fc_b[e]) ----
__global__ void routing_kernel(const float* __restrict__ gap, const float* __restrict__ fcw,
                               const float* __restrict__ fcb, float* __restrict__ rout) {
    int t = threadIdx.x;           // 256 threads: (b,e)
    int b = t >> 3, e = t & 7;
    const float* g = gap + b * CIN;
    const float* w = fcw + e * CIN;
    float z = 0.f;
    for (int c = 0; c < CIN; ++c) z += g[c] * w[c];
    z = z * (1.0f / 3136.0f) + fcb[e];
    rout[b * NEXP + e] = 1.f / (1.f + expf(-z));
}

// ---- cmb[b][o][r][i] = sum_e rout[b][e] * kw[e][o][i][r]  (bf16) ----
__global__ void combine_kernel(const float* __restrict__ kw, const float* __restrict__ rout,
                               unsigned short* __restrict__ cmb) {
    int o = blockIdx.x;
    int t = threadIdx.x;
    __shared__ float rs[BATCH][NEXP];
    rs[t >> 3][t & 7] = rout[t];
    __syncthreads();
    for (int r = 0; r < 9; ++r) {
        int i = t;
        float kv[NEXP];
        #pragma unroll
        for (int e = 0; e < NEXP; ++e)
            kv[e] = kw[(((size_t)e * COUT + o) * CIN + i) * 9 + r];
        for (int b = 0; b < BATCH; ++b) {
            float s = 0.f;
            #pragma unroll
            for (int e = 0; e < NEXP; ++e) s += rs[b][e] * kv[e];
            cmb[(((size_t)b * COUT + o) * 9 + r) * CIN + i] = f32_to_bf16(s);
        }
    }
}

// ---- conv: implicit GEMM, NO LDS, NO barriers. Operands stream from L1/L2/L3. ----
// Block: 256 thr (4 waves, 2M x 2N). Block tile M=128 o, N=224 px (28h x 8w).
// Wave tile: 64 o x 112 px = 4m x 7n fragments (16x16x32 bf16 MFMA).
__global__ __launch_bounds__(256, 2)
void conv_kernel(const unsigned short* __restrict__ xtp, const unsigned short* __restrict__ cmb,
                 float* __restrict__ out) {
    int t = threadIdx.x;
    int wave = t >> 6, l = t & 63, lr = l & 15, lk = l >> 4;
    int wm = wave >> 1, wn = wave & 1;
    int b = blockIdx.z;
    int o0 = blockIdx.y * 128 + wm * 64;
    int ht = blockIdx.x / 7, wt = blockIdx.x - ht * 7;
    int oh0 = ht * 28 + wn * 14, ow0 = wt * 8;

    // A fragment pointers: row = o0 + m*16 + lr (o), k-chunk lk (8 i elems)
    const unsigned short* ap[4];
    #pragma unroll
    for (int m = 0; m < 4; ++m)
        ap[m] = cmb + ((size_t)(b * COUT + o0 + m * 16 + lr)) * KTOT + lk * 8;

    // B fragment pointers: pixel col = lr -> (2h x 8w), k-chunk lk
    const unsigned short* bp[7];
    #pragma unroll
    for (int nt = 0; nt < 7; ++nt)
        bp[nt] = xtp + (((size_t)b * HP + (oh0 + nt * 2 + (lr >> 3))) * HP
                        + (ow0 + (lr & 7))) * CIN + lk * 8;

    f32x4 acc[4][7];
    #pragma unroll
    for (int m = 0; m < 4; ++m)
        #pragma unroll
        for (int nt = 0; nt < 7; ++nt) acc[m][nt] = (f32x4){0.f, 0.f, 0.f, 0.f};

    for (int ib = 0; ib < 8; ++ib) {
        #pragma unroll
        for (int r = 0; r < 9; ++r) {
            const int dh = r / 3, dw = r - (r / 3) * 3;
            const int aoff = r * CIN + ib * 32;            // elems
            const int boff = (dh * HP + dw) * CIN + ib * 32;
            bf16x8 a[4], bq[7];
            #pragma unroll
            for (int m = 0; m < 4; ++m)
                a[m] = __builtin_bit_cast(bf16x8,
                        *reinterpret_cast<const u16x8*>(ap[m] + aoff));
            #pragma unroll
            for (int nt = 0; nt < 7; ++nt)
                bq[nt] = __builtin_bit_cast(bf16x8,
                        *reinterpret_cast<const u16x8*>(bp[nt] + boff));
            #pragma unroll
            for (int nt = 0; nt < 7; ++nt)
                #pragma unroll
                for (int m = 0; m < 4; ++m)
                    acc[m][nt] = __builtin_amdgcn_mfma_f32_16x16x32_bf16(a[m], bq[nt], acc[m][nt], 0, 0, 0);
        }
    }

    // epilogue: D col = lane&15 (pixel), row = (lane>>4)*4 + reg (o)
    #pragma unroll
    for (int m = 0; m < 4; ++m) {
        #pragma unroll
        for (int nt = 0; nt < 7; ++nt) {
            int oh = oh0 + nt * 2 + (lr >> 3), ow = ow0 + (lr & 7);
            float* op = out + ((size_t)(b * COUT + o0 + m * 16 + lk * 4)) * (HW * HW)
                        + oh * HW + ow;
            #pragma unroll
            for (int reg = 0; reg < 4; ++reg)
                op[(size_t)reg * (HW * HW)] = acc[m][nt][reg];
        }
    }
}

extern "C" void kernel_launch(void* const* d_in, const int* in_sizes, int n_in,
                              void* d_out, int out_size, void* d_ws, size_t ws_size,
                              hipStream_t stream) {
    const float* x   = (const float*)d_in[0];
    const float* kw  = (const float*)d_in[1];
    const float* fcw = (const float*)d_in[2];
    const float* fcb = (const float*)d_in[3];
    float* out = (float*)d_out;

    // workspace layout (bytes, 256-aligned)
    char* ws = (char*)d_ws;
    float* gap  = (float*)(ws + 0);                        //  32768 B
    float* rout = (float*)(ws + 32768);                    //   1024 B
    unsigned short* cmb = (unsigned short*)(ws + 33792);   // 37748736 B
    unsigned short* xtp = (unsigned short*)(ws + 33792 + 37748736); // 55107584 B

    hipMemsetAsync(gap, 0, BATCH * CIN * sizeof(float), stream);
    transpose_kernel<<<dim3(HP, 8, BATCH), 256, 0, stream>>>(x, xtp, gap);
    routing_kernel<<<1, 256, 0, stream>>>(gap, fcw, fcb, rout);
    combine_kernel<<<COUT, 256, 0, stream>>>(kw, rout, cmb);
    conv_kernel<<<dim3(14, 2, BATCH), 256, 0, stream>>>(xtp, cmb, out);
}